// Round 1
// baseline (972.904 us; speedup 1.0000x reference)
//
#include <hip/hip_runtime.h>
#include <math.h>

#define BB 256
#define SS 30
#define CC 62
#define LL 169
#define OG 64
#define OH 64
#define KK1 64
#define KK2 32
#define KK3 14
#define T12LEN 95    // 64+32-1
#define FLEN 108     // 64+32+14-2

// ---------------- setup kernels (build effective filter F, bias beff, g23) ----------------

// T[c1][c0][k'] = pw1_w[c1,c0] * sum_{k2} dw2_w[c1,k2] * dw1_w[c0,k'-k2]
__global__ void k_setup_T(const float* __restrict__ dw1, const float* __restrict__ dw2,
                          const float* __restrict__ pw1, float* __restrict__ Tbuf) {
    int c1 = blockIdx.x / CC, c0 = blockIdx.x % CC;
    int kp = threadIdx.x;
    if (kp >= T12LEN) return;
    int k2lo = max(0, kp - (KK1 - 1));
    int k2hi = min(KK2 - 1, kp);
    float s = 0.f;
    for (int k2 = k2lo; k2 <= k2hi; ++k2)
        s += dw2[c1 * KK2 + k2] * dw1[c0 * KK1 + (kp - k2)];
    Tbuf[(c1 * CC + c0) * T12LEN + kp] = s * pw1[c1 * CC + c0];
}

// g23[c1][k3] = sum_{c2} pw3_w[61,c2] * pw2_w[c2,c1] * dw3_w[c2,k3]   and  beff (scalar bias chain)
__global__ void k_setup_g(const float* __restrict__ pw2, const float* __restrict__ pw3,
                          const float* __restrict__ dw3,
                          const float* __restrict__ dw1b, const float* __restrict__ pw1w,
                          const float* __restrict__ pw1b,
                          const float* __restrict__ dw2, const float* __restrict__ dw2b,
                          const float* __restrict__ pw2b,
                          const float* __restrict__ dw3b, const float* __restrict__ pw3b,
                          float* __restrict__ g23, float* __restrict__ beff) {
    __shared__ float by2[CC], vals[CC];
    int tid = threadIdx.x;
    for (int idx = tid; idx < CC * KK3; idx += blockDim.x) {
        int c1 = idx / KK3, k3 = idx % KK3;
        float s = 0.f;
        for (int c2 = 0; c2 < CC; ++c2)
            s += pw3[61 * CC + c2] * pw2[c2 * CC + c1] * dw3[c2 * KK3 + k3];
        g23[idx] = s;
    }
    if (tid < CC) {
        int c1 = tid;
        float bz1 = pw1b[c1];
        for (int c0 = 0; c0 < CC; ++c0) bz1 += pw1w[c1 * CC + c0] * dw1b[c0];
        float s2 = 0.f;
        for (int k = 0; k < KK2; ++k) s2 += dw2[c1 * KK2 + k];
        by2[c1] = dw2b[c1] + bz1 * s2;
    }
    __syncthreads();
    if (tid < CC) {
        int c2 = tid;
        float bz2 = pw2b[c2];
        for (int c1 = 0; c1 < CC; ++c1) bz2 += pw2[c2 * CC + c1] * by2[c1];
        float s3 = 0.f;
        for (int k = 0; k < KK3; ++k) s3 += dw3[c2 * KK3 + k];
        vals[c2] = pw3[61 * CC + c2] * (dw3b[c2] + bz2 * s3);
    }
    __syncthreads();
    if (tid == 0) {
        float s = pw3b[61];
        for (int c2 = 0; c2 < CC; ++c2) s += vals[c2];
        *beff = s;
    }
}

// F[c0][o] = sum_{c1,k3} g23[c1,k3] * T[c1][c0][o-k3]
__global__ void k_setup_F(const float* __restrict__ Tbuf, const float* __restrict__ g23,
                          float* __restrict__ F) {
    __shared__ float gl[CC * KK3];
    int c0 = blockIdx.x;
    for (int i = threadIdx.x; i < CC * KK3; i += blockDim.x) gl[i] = g23[i];
    __syncthreads();
    int o = threadIdx.x;
    if (o >= FLEN) return;
    float s = 0.f;
    int k3hi = min(KK3 - 1, o);
    int k3lo = max(0, o - (T12LEN - 1));
    for (int c1 = 0; c1 < CC; ++c1) {
        const float* Trow = Tbuf + (c1 * CC + c0) * T12LEN;
        for (int k3 = k3lo; k3 <= k3hi; ++k3)
            s += gl[c1 * KK3 + k3] * Trow[o - k3];
    }
    F[c0 * FLEN + o] = s;
}

// ---------------- main parallel phase: one block per (b,t) ----------------
// Produces per-gate pre-activation halves: gates[gate][t][b][f]
//   = (gf @ Wg[:, :64]^T)[f] + Wg_b[f] + b_g[f]
__global__ __launch_bounds__(256) void k_main(
        const float* __restrict__ x, const float* __restrict__ adj,
        const float* __restrict__ F, const float* __restrict__ beff_p,
        const float* __restrict__ gcnw, const float* __restrict__ gcnb,
        const float* __restrict__ Wr, const float* __restrict__ Wrb, const float* __restrict__ br,
        const float* __restrict__ Wu, const float* __restrict__ Wub, const float* __restrict__ bu,
        const float* __restrict__ Wc, const float* __restrict__ Wcb, const float* __restrict__ bc,
        float* __restrict__ gates) {
    __shared__ __align__(16) float xt[CC * LL];   // 10478 floats
    __shared__ float adjt[CC];
    __shared__ float wx[LL];
    __shared__ float glds[OG];
    int bt = blockIdx.x;            // b*SS + t
    int b = bt / SS, t = bt % SS;
    int tid = threadIdx.x;
    const float* xg = x + (size_t)bt * (CC * LL);

    // stage x tile (10478 floats, even -> float2 aligned: byte off = bt*41912, %8==0)
    {
        const float2* xg2 = (const float2*)xg;
        float2* xt2 = (float2*)xt;
        for (int i = tid; i < (CC * LL) / 2; i += 256) xt2[i] = xg2[i];
    }
    __syncthreads();

    // d_row[j] via effective Toeplitz filter; 4 lanes per j (c-split), shuffle reduce
    if (tid < 4 * CC) {
        int j = tid >> 2, q = tid & 3;
        float acc = 0.f;
        for (int c = q; c < CC; c += 4) {
            const float4* Fr = (const float4*)(F + c * FLEN);
            const float* xr = xt + c * LL + j;
            float s0 = 0.f, s1 = 0.f, s2 = 0.f, s3 = 0.f;
            #pragma unroll 9
            for (int o4 = 0; o4 < FLEN / 4; ++o4) {
                float4 fv = Fr[o4];
                s0 += fv.x * xr[o4 * 4 + 0];
                s1 += fv.y * xr[o4 * 4 + 1];
                s2 += fv.z * xr[o4 * 4 + 2];
                s3 += fv.w * xr[o4 * 4 + 3];
            }
            acc += (s0 + s1) + (s2 + s3);
        }
        acc += __shfl_xor(acc, 1);
        acc += __shfl_xor(acc, 2);
        if (q == 0) {
            float v = acc + *beff_p + adj[61 * CC + j];
            adjt[j] = 1.f / (1.f + __expf(-v));
        }
    }
    __syncthreads();

    // wx[l] = sum_j adjt[j] * xt[j][l]
    if (tid < LL) {
        float s = 0.f;
        for (int j = 0; j < CC; ++j) s += adjt[j] * xt[j * LL + tid];
        wx[tid] = s;
    }
    __syncthreads();

    // g[f] = gcn_b[f] + sum_l wx[l] * gcn_w[l,f]
    if (tid < OG) {
        float s = gcnb[tid];
        for (int l = 0; l < LL; ++l) s += wx[l] * gcnw[l * OG + tid];
        glds[tid] = s;
    }
    __syncthreads();

    // per-gate gf-half pre-activations (+ all biases)
    if (tid < 3 * OH) {
        int gate = tid >> 6, f = tid & 63;
        const float* W  = gate == 0 ? Wr  : (gate == 1 ? Wu  : Wc);
        const float* Wb = gate == 0 ? Wrb : (gate == 1 ? Wub : Wcb);
        const float* bb = gate == 0 ? br  : (gate == 1 ? bu  : bc);
        float s = Wb[f] + bb[f];
        for (int i = 0; i < OG; ++i) s += glds[i] * W[f * (OG + OH) + i];
        gates[((size_t)(gate * SS + t) * BB + b) * OH + f] = s;
    }
}

// ---------------- sequential GRU scan over t (tiny): one block per batch row ----------------
__global__ __launch_bounds__(256) void k_scan(
        const float* __restrict__ gates,
        const float* __restrict__ Wr, const float* __restrict__ Wu, const float* __restrict__ Wc,
        float* __restrict__ out) {
    __shared__ float hl[OH], rhl[OH];
    int b = blockIdx.x;
    int tid = threadIdx.x;
    int f = tid >> 2, q = tid & 3;
    // register-resident h-half weight slices: W*[f][64 + q*16 + i]
    float wr[16], wu[16], wc[16];
    #pragma unroll
    for (int i = 0; i < 16; ++i) {
        int col = OG + q * 16 + i;
        wr[i] = Wr[f * (OG + OH) + col];
        wu[i] = Wu[f * (OG + OH) + col];
        wc[i] = Wc[f * (OG + OH) + col];
    }
    float h = 0.f;
    if (tid < OH) hl[tid] = 0.f;
    __syncthreads();
    const float* Gr = gates;
    const float* Gu = gates + (size_t)SS * BB * OH;
    const float* Gc = gates + (size_t)2 * SS * BB * OH;
    for (int t = 0; t < SS; ++t) {
        float gr = Gr[((size_t)t * BB + b) * OH + f];
        float gu = Gu[((size_t)t * BB + b) * OH + f];
        float gc = Gc[((size_t)t * BB + b) * OH + f];
        float rv = 0.f, uv = 0.f;
        #pragma unroll
        for (int i = 0; i < 16; ++i) {
            float hv = hl[q * 16 + i];
            rv += wr[i] * hv;
            uv += wu[i] * hv;
        }
        rv += __shfl_xor(rv, 1); rv += __shfl_xor(rv, 2);
        uv += __shfl_xor(uv, 1); uv += __shfl_xor(uv, 2);
        float r = 1.f / (1.f + __expf(-(rv + gr)));
        float u = 1.f / (1.f + __expf(-(uv + gu)));
        if (q == 0) rhl[f] = r * h;
        __syncthreads();
        float cv = 0.f;
        #pragma unroll
        for (int i = 0; i < 16; ++i) cv += wc[i] * rhl[q * 16 + i];
        cv += __shfl_xor(cv, 1); cv += __shfl_xor(cv, 2);
        float cc = tanhf(cv + gc);
        if (q == 0) {
            h = u * h + (1.f - u) * cc;
            hl[f] = h;
        }
        __syncthreads();
    }
    if (q == 0) out[b * OH + f] = h;
}

extern "C" void kernel_launch(void* const* d_in, const int* in_sizes, int n_in,
                              void* d_out, int out_size, void* d_ws, size_t ws_size,
                              hipStream_t stream) {
    const float* x    = (const float*)d_in[0];
    const float* adj  = (const float*)d_in[1];
    const float* dw1w = (const float*)d_in[2];
    const float* dw1b = (const float*)d_in[3];
    const float* pw1w = (const float*)d_in[4];
    const float* pw1b = (const float*)d_in[5];
    const float* dw2w = (const float*)d_in[6];
    const float* dw2b = (const float*)d_in[7];
    const float* pw2w = (const float*)d_in[8];
    const float* pw2b = (const float*)d_in[9];
    const float* dw3w = (const float*)d_in[10];
    const float* dw3b = (const float*)d_in[11];
    const float* pw3w = (const float*)d_in[12];
    const float* pw3b = (const float*)d_in[13];
    const float* gcnw = (const float*)d_in[14];
    const float* gcnb = (const float*)d_in[15];
    const float* Wrw  = (const float*)d_in[16];
    const float* Wrb  = (const float*)d_in[17];
    const float* Wuw  = (const float*)d_in[18];
    const float* Wub  = (const float*)d_in[19];
    const float* Wcw  = (const float*)d_in[20];
    const float* Wcb  = (const float*)d_in[21];
    const float* br   = (const float*)d_in[22];
    const float* bu   = (const float*)d_in[23];
    const float* bc   = (const float*)d_in[24];
    float* out = (float*)d_out;

    // workspace layout (bytes)
    char* ws = (char*)d_ws;
    float* Tbuf  = (float*)(ws + 0);                 // 62*62*95 = 365180 floats
    float* g23   = (float*)(ws + 1460736);           // 868 floats
    float* beff  = (float*)(ws + 1464320);           // 1 float
    float* F     = (float*)(ws + 1464576);           // 6696 floats (16B aligned)
    float* gates = (float*)(ws + 1491456);           // 3*30*256*64 = 1474560 floats
    (void)ws_size; (void)in_sizes; (void)n_in; (void)out_size;

    k_setup_T<<<CC * CC, 128, 0, stream>>>(dw1w, dw2w, pw1w, Tbuf);
    k_setup_g<<<1, 1024, 0, stream>>>(pw2w, pw3w, dw3w, dw1b, pw1w, pw1b,
                                      dw2w, dw2b, pw2b, dw3b, pw3b, g23, beff);
    k_setup_F<<<CC, 128, 0, stream>>>(Tbuf, g23, F);
    k_main<<<BB * SS, 256, 0, stream>>>(x, adj, F, beff, gcnw, gcnb,
                                        Wrw, Wrb, br, Wuw, Wub, bu, Wcw, Wcb, bc, gates);
    k_scan<<<BB, 256, 0, stream>>>(gates, Wrw, Wuw, Wcw, out);
}

// Round 2
// 682.248 us; speedup vs baseline: 1.4260x; 1.4260x over previous
//
#include <hip/hip_runtime.h>
#include <math.h>

#define BB 256
#define SS 30
#define CC 62
#define LL 169
#define OG 64
#define OH 64
#define KK1 64
#define KK2 32
#define KK3 14
#define T12LEN 95    // 64+32-1
#define FLEN 108     // 64+32+14-2
#define XSTR 180     // padded LDS row stride (dwords): %4==0, 180%32=20 -> uniform banks

// ---------------- setup kernels ----------------

// T[c1][c0][k'] = pw1_w[c1,c0] * sum_{k2} dw2_w[c1,k2] * dw1_w[c0,k'-k2]
__global__ void k_setup_T(const float* __restrict__ dw1, const float* __restrict__ dw2,
                          const float* __restrict__ pw1, float* __restrict__ Tbuf) {
    int c1 = blockIdx.x / CC, c0 = blockIdx.x % CC;
    int kp = threadIdx.x;
    if (kp >= T12LEN) return;
    int k2lo = max(0, kp - (KK1 - 1));
    int k2hi = min(KK2 - 1, kp);
    float s = 0.f;
    for (int k2 = k2lo; k2 <= k2hi; ++k2)
        s += dw2[c1 * KK2 + k2] * dw1[c0 * KK1 + (kp - k2)];
    Tbuf[(c1 * CC + c0) * T12LEN + kp] = s * pw1[c1 * CC + c0];
}

// g23[c1][k3] = sum_{c2} pw3_w[61,c2] * pw2_w[c2,c1] * dw3_w[c2,k3]   and  beff
__global__ void k_setup_g(const float* __restrict__ pw2, const float* __restrict__ pw3,
                          const float* __restrict__ dw3,
                          const float* __restrict__ dw1b, const float* __restrict__ pw1w,
                          const float* __restrict__ pw1b,
                          const float* __restrict__ dw2, const float* __restrict__ dw2b,
                          const float* __restrict__ pw2b,
                          const float* __restrict__ dw3b, const float* __restrict__ pw3b,
                          float* __restrict__ g23, float* __restrict__ beff) {
    __shared__ float by2[CC], vals[CC];
    int tid = threadIdx.x;
    for (int idx = tid; idx < CC * KK3; idx += blockDim.x) {
        int c1 = idx / KK3, k3 = idx % KK3;
        float s = 0.f;
        for (int c2 = 0; c2 < CC; ++c2)
            s += pw3[61 * CC + c2] * pw2[c2 * CC + c1] * dw3[c2 * KK3 + k3];
        g23[idx] = s;
    }
    if (tid < CC) {
        int c1 = tid;
        float bz1 = pw1b[c1];
        for (int c0 = 0; c0 < CC; ++c0) bz1 += pw1w[c1 * CC + c0] * dw1b[c0];
        float s2 = 0.f;
        for (int k = 0; k < KK2; ++k) s2 += dw2[c1 * KK2 + k];
        by2[c1] = dw2b[c1] + bz1 * s2;
    }
    __syncthreads();
    if (tid < CC) {
        int c2 = tid;
        float bz2 = pw2b[c2];
        for (int c1 = 0; c1 < CC; ++c1) bz2 += pw2[c2 * CC + c1] * by2[c1];
        float s3 = 0.f;
        for (int k = 0; k < KK3; ++k) s3 += dw3[c2 * KK3 + k];
        vals[c2] = pw3[61 * CC + c2] * (dw3b[c2] + bz2 * s3);
    }
    __syncthreads();
    if (tid == 0) {
        float s = pw3b[61];
        for (int c2 = 0; c2 < CC; ++c2) s += vals[c2];
        *beff = s;
    }
}

// F[c0][o] = sum_{c1,k3} g23[c1,k3] * T[c1][c0][o-k3]
__global__ void k_setup_F(const float* __restrict__ Tbuf, const float* __restrict__ g23,
                          float* __restrict__ F) {
    __shared__ float gl[CC * KK3];
    int c0 = blockIdx.x;
    for (int i = threadIdx.x; i < CC * KK3; i += blockDim.x) gl[i] = g23[i];
    __syncthreads();
    int o = threadIdx.x;
    if (o >= FLEN) return;
    float s = 0.f;
    int k3hi = min(KK3 - 1, o);
    int k3lo = max(0, o - (T12LEN - 1));
    for (int c1 = 0; c1 < CC; ++c1) {
        const float* Trow = Tbuf + (c1 * CC + c0) * T12LEN;
        for (int k3 = k3lo; k3 <= k3hi; ++k3)
            s += gl[c1 * KK3 + k3] * Trow[o - k3];
    }
    F[c0 * FLEN + o] = s;
}

// Wt[gate][i][f] = W_gate[f][i]  (first-64-col half, transposed for coalesced reads)
__global__ void k_setup_Wt(const float* __restrict__ Wr, const float* __restrict__ Wu,
                           const float* __restrict__ Wc, float* __restrict__ Wt) {
    int gate = blockIdx.x;
    const float* W = gate == 0 ? Wr : (gate == 1 ? Wu : Wc);
    for (int idx = threadIdx.x; idx < OG * OH; idx += blockDim.x) {
        int i = idx >> 6, f = idx & 63;
        Wt[gate * OG * OH + idx] = W[f * (OG + OH) + i];
    }
}

// ---------------- main parallel phase: one block per (b,t) ----------------
__global__ __launch_bounds__(256) void k_main(
        const float* __restrict__ x, const float* __restrict__ adj,
        const float* __restrict__ F, const float* __restrict__ beff_p,
        const float* __restrict__ gcnw, const float* __restrict__ gcnb,
        const float* __restrict__ Wtr,
        const float* __restrict__ Wrb, const float* __restrict__ br,
        const float* __restrict__ Wub, const float* __restrict__ bu,
        const float* __restrict__ Wcb, const float* __restrict__ bc,
        float* __restrict__ gates) {
    __shared__ __align__(16) float xt[CC * XSTR];    // 44640 B
    __shared__ __align__(16) float Fl[CC * FLEN];    // 26784 B
    __shared__ float dpart[4][64];
    __shared__ float adjt[CC];
    __shared__ float wx[LL];
    __shared__ float gpart[4][OG];
    __shared__ float glds[OG];

    int bt = blockIdx.x;            // b*SS + t
    int b = bt / SS, t = bt % SS;
    int tid = threadIdx.x;
    const float* xg = x + (size_t)bt * (CC * LL);

    // stage x into padded rows (coalesced global reads)
    for (int idx = tid; idx < CC * LL; idx += 256) {
        int c = idx / LL;
        int l = idx - c * LL;
        xt[c * XSTR + l] = xg[idx];
    }
    // stage F (16B-aligned)
    {
        const float4* Fg = (const float4*)F;
        float4* Fl4 = (float4*)Fl;
        for (int i = tid; i < (CC * FLEN) / 4; i += 256) Fl4[i] = Fg[i];
    }
    __syncthreads();

    // ---- d_row: J=16 register-tiled correlation, one c per lane ----
    int lane = tid & 63, wid = tid >> 6;
    int jp = lane & 3, lg = lane >> 2;
    int c = wid * 16 + lg;          // 0..63, mask c<62
    int j0 = 16 * jp;
    float acc[16];
    #pragma unroll
    for (int k = 0; k < 16; ++k) acc[k] = 0.f;

    if (c < CC) {
        const float* rp = xt + c * XSTR + j0;
        const float* fp = Fl + c * FLEN;
        float e[20];
        {
            float4 v0 = *(const float4*)(rp + 0);
            float4 v1 = *(const float4*)(rp + 4);
            float4 v2 = *(const float4*)(rp + 8);
            float4 v3 = *(const float4*)(rp + 12);
            e[0]=v0.x; e[1]=v0.y; e[2]=v0.z; e[3]=v0.w;
            e[4]=v1.x; e[5]=v1.y; e[6]=v1.z; e[7]=v1.w;
            e[8]=v2.x; e[9]=v2.y; e[10]=v2.z; e[11]=v2.w;
            e[12]=v3.x; e[13]=v3.y; e[14]=v3.z; e[15]=v3.w;
        }
        #pragma unroll
        for (int m = 0; m < 27; ++m) {
            float4 nv = *(const float4*)(rp + 4 * m + 16);
            e[16]=nv.x; e[17]=nv.y; e[18]=nv.z; e[19]=nv.w;
            float4 fq = *(const float4*)(fp + 4 * m);
            #pragma unroll
            for (int k = 0; k < 16; ++k)
                acc[k] += fq.x * e[k] + fq.y * e[k+1] + fq.z * e[k+2] + fq.w * e[k+3];
            #pragma unroll
            for (int i = 0; i < 16; ++i) e[i] = e[i + 4];
        }
    }
    // reduce over lg (lane bits 2..5)
    #pragma unroll
    for (int k = 0; k < 16; ++k) {
        acc[k] += __shfl_xor(acc[k], 4);
        acc[k] += __shfl_xor(acc[k], 8);
        acc[k] += __shfl_xor(acc[k], 16);
        acc[k] += __shfl_xor(acc[k], 32);
    }
    if (lg == 0) {
        #pragma unroll
        for (int k = 0; k < 16; ++k) dpart[wid][j0 + k] = acc[k];
    }
    __syncthreads();

    if (tid < CC) {
        float d = dpart[0][tid] + dpart[1][tid] + dpart[2][tid] + dpart[3][tid];
        float v = d + *beff_p + adj[61 * CC + tid];
        adjt[tid] = 1.f / (1.f + __expf(-v));
    }
    __syncthreads();

    // wx[l] = sum_j adjt[j] * xt[j][l]
    if (tid < LL) {
        float s = 0.f;
        #pragma unroll 2
        for (int j = 0; j < CC; ++j) s += adjt[j] * xt[j * XSTR + tid];
        wx[tid] = s;
    }
    __syncthreads();

    // g[f] = gcn_b[f] + sum_l wx[l] * gcn_w[l,f]   (l split over 4 thread groups)
    {
        int f = tid & 63, lq = tid >> 6;
        float s = 0.f;
        for (int l = lq; l < LL; l += 4) s += wx[l] * gcnw[l * OG + f];
        gpart[lq][f] = s;
    }
    __syncthreads();
    if (tid < OG)
        glds[tid] = gcnb[tid] + gpart[0][tid] + gpart[1][tid] + gpart[2][tid] + gpart[3][tid];
    __syncthreads();

    // per-gate gf-half pre-activations (+ all biases), transposed weights
    if (tid < 3 * OH) {
        int gate = tid >> 6, f = tid & 63;
        const float* Wt = Wtr + gate * OG * OH;
        const float* Wb = gate == 0 ? Wrb : (gate == 1 ? Wub : Wcb);
        const float* bb = gate == 0 ? br  : (gate == 1 ? bu  : bc);
        float s = Wb[f] + bb[f];
        #pragma unroll 4
        for (int i = 0; i < OG; ++i) s += glds[i] * Wt[i * OH + f];
        gates[((size_t)(gate * SS + t) * BB + b) * OH + f] = s;
    }
}

// ---------------- sequential GRU scan over t: one block per batch row ----------------
__global__ __launch_bounds__(256) void k_scan(
        const float* __restrict__ gates,
        const float* __restrict__ Wr, const float* __restrict__ Wu, const float* __restrict__ Wc,
        float* __restrict__ out) {
    __shared__ float hl[OH], rhl[OH];
    int b = blockIdx.x;
    int tid = threadIdx.x;
    int f = tid >> 2, q = tid & 3;
    float wr[16], wu[16], wc[16];
    #pragma unroll
    for (int i = 0; i < 16; ++i) {
        int col = OG + q * 16 + i;
        wr[i] = Wr[f * (OG + OH) + col];
        wu[i] = Wu[f * (OG + OH) + col];
        wc[i] = Wc[f * (OG + OH) + col];
    }
    float h = 0.f;
    if (tid < OH) hl[tid] = 0.f;
    __syncthreads();
    const float* Gr = gates;
    const float* Gu = gates + (size_t)SS * BB * OH;
    const float* Gc = gates + (size_t)2 * SS * BB * OH;
    for (int t = 0; t < SS; ++t) {
        float gr = Gr[((size_t)t * BB + b) * OH + f];
        float gu = Gu[((size_t)t * BB + b) * OH + f];
        float gc = Gc[((size_t)t * BB + b) * OH + f];
        float rv = 0.f, uv = 0.f;
        #pragma unroll
        for (int i = 0; i < 16; ++i) {
            float hv = hl[q * 16 + i];
            rv += wr[i] * hv;
            uv += wu[i] * hv;
        }
        rv += __shfl_xor(rv, 1); rv += __shfl_xor(rv, 2);
        uv += __shfl_xor(uv, 1); uv += __shfl_xor(uv, 2);
        float r = 1.f / (1.f + __expf(-(rv + gr)));
        float u = 1.f / (1.f + __expf(-(uv + gu)));
        if (q == 0) rhl[f] = r * h;
        __syncthreads();
        float cv = 0.f;
        #pragma unroll
        for (int i = 0; i < 16; ++i) cv += wc[i] * rhl[q * 16 + i];
        cv += __shfl_xor(cv, 1); cv += __shfl_xor(cv, 2);
        float cc = tanhf(cv + gc);
        if (q == 0) {
            h = u * h + (1.f - u) * cc;
            hl[f] = h;
        }
        __syncthreads();
    }
    if (q == 0) out[b * OH + f] = h;
}

extern "C" void kernel_launch(void* const* d_in, const int* in_sizes, int n_in,
                              void* d_out, int out_size, void* d_ws, size_t ws_size,
                              hipStream_t stream) {
    const float* x    = (const float*)d_in[0];
    const float* adj  = (const float*)d_in[1];
    const float* dw1w = (const float*)d_in[2];
    const float* dw1b = (const float*)d_in[3];
    const float* pw1w = (const float*)d_in[4];
    const float* pw1b = (const float*)d_in[5];
    const float* dw2w = (const float*)d_in[6];
    const float* dw2b = (const float*)d_in[7];
    const float* pw2w = (const float*)d_in[8];
    const float* pw2b = (const float*)d_in[9];
    const float* dw3w = (const float*)d_in[10];
    const float* dw3b = (const float*)d_in[11];
    const float* pw3w = (const float*)d_in[12];
    const float* pw3b = (const float*)d_in[13];
    const float* gcnw = (const float*)d_in[14];
    const float* gcnb = (const float*)d_in[15];
    const float* Wrw  = (const float*)d_in[16];
    const float* Wrb  = (const float*)d_in[17];
    const float* Wuw  = (const float*)d_in[18];
    const float* Wub  = (const float*)d_in[19];
    const float* Wcw  = (const float*)d_in[20];
    const float* Wcb  = (const float*)d_in[21];
    const float* br   = (const float*)d_in[22];
    const float* bu   = (const float*)d_in[23];
    const float* bc   = (const float*)d_in[24];
    float* out = (float*)d_out;

    // workspace layout (bytes)
    char* ws = (char*)d_ws;
    float* Tbuf  = (float*)(ws + 0);                 // 365180 floats
    float* g23   = (float*)(ws + 1460736);           // 868 floats
    float* beff  = (float*)(ws + 1464320);           // 1 float
    float* F     = (float*)(ws + 1464576);           // 6696 floats (16B aligned)
    float* gates = (float*)(ws + 1491456);           // 1474560 floats
    float* Wt    = (float*)(ws + 7389696);           // 3*64*64 = 12288 floats
    (void)ws_size; (void)in_sizes; (void)n_in; (void)out_size;

    k_setup_T<<<CC * CC, 128, 0, stream>>>(dw1w, dw2w, pw1w, Tbuf);
    k_setup_g<<<1, 1024, 0, stream>>>(pw2w, pw3w, dw3w, dw1b, pw1w, pw1b,
                                      dw2w, dw2b, pw2b, dw3b, pw3b, g23, beff);
    k_setup_F<<<CC, 128, 0, stream>>>(Tbuf, g23, F);
    k_setup_Wt<<<3, 256, 0, stream>>>(Wrw, Wuw, Wcw, Wt);
    k_main<<<BB * SS, 256, 0, stream>>>(x, adj, F, beff, gcnw, gcnb, Wt,
                                        Wrb, br, Wub, bu, Wcb, bc, gates);
    k_scan<<<BB, 256, 0, stream>>>(gates, Wrw, Wuw, Wcw, out);
}